// Round 8
// baseline (566.209 us; speedup 1.0000x reference)
//
#include <hip/hip_runtime.h>

typedef unsigned short u16;
typedef __attribute__((ext_vector_type(8))) short short8;
typedef __attribute__((ext_vector_type(4))) float f32x4;

#define MFMA16(a, b, c) __builtin_amdgcn_mfma_f32_16x16x32_bf16(a, b, c, 0, 0, 0)

__device__ __forceinline__ float bf2f(u16 u) {
    return __uint_as_float(((unsigned)u) << 16);
}
__device__ __forceinline__ u16 f2bf(float f) {
    unsigned u = __float_as_uint(f);
    u += 0x7fff + ((u >> 16) & 1);
    return (u16)(u >> 16);
}

// convert mem & pos (f32, 8388608 elems each) to bf16. grid 8192 x 256.
__global__ __launch_bounds__(256) void cvt2(const float* __restrict__ a,
                                            const float* __restrict__ b,
                                            u16* __restrict__ A, u16* __restrict__ B) {
    size_t i = ((size_t)blockIdx.x * 256 + threadIdx.x) * 4;
    float4 va = *(const float4*)(a + i);
    float4 vb = *(const float4*)(b + i);
    u16 ta[4] = {f2bf(va.x), f2bf(va.y), f2bf(va.z), f2bf(va.w)};
    u16 tb[4] = {f2bf(vb.x), f2bf(vb.y), f2bf(vb.z), f2bf(vb.w)};
    *(uint2*)(A + i) = *(uint2*)ta;
    *(uint2*)(B + i) = *(uint2*)tb;
}

// ---------------------------------------------------------------------------
// Fold kernels v3: collapse (proj -> concat -> proj) into bf16 weights stored
// TRANSPOSED ([N][K]).
// ---------------------------------------------------------------------------

// WQ3T[512][768]: k<256: w_qc@wqC ; 256..511: w_qp@wqC ; 512..767: w_qs@wqS (x 1/8)
__global__ __launch_bounds__(256) void fold_q(const float* __restrict__ w_qc,
                                              const float* __restrict__ w_qp,
                                              const float* __restrict__ w_qs,
                                              const float* __restrict__ wq,
                                              u16* __restrict__ WQ3T) {
    int o = blockIdx.x * 256 + threadIdx.x;
    int k0 = blockIdx.y * 4;
    int seg = k0 >> 8, kb = k0 & 255;
    const float* wsrc = (seg == 0) ? w_qc : ((seg == 1) ? w_qp : w_qs);
    int sOff = (seg == 2) ? 32 : 0;
    const float* wcol = wq + o;
    float acc[4] = {0.f, 0.f, 0.f, 0.f};
#pragma unroll 8
    for (int c = 0; c < 256; c++) {
        int mc = (c >> 5) * 64 + (c & 31) + sOff;
        float w0 = wcol[(size_t)mc * 512];
#pragma unroll
        for (int j = 0; j < 4; j++)
            acc[j] += wsrc[(size_t)(kb + j) * 256 + c] * w0;
    }
    u16 outv[4];
#pragma unroll
    for (int j = 0; j < 4; j++) outv[j] = f2bf(acc[j] * 0.125f);
    *(uint2*)(WQ3T + (size_t)o * 768 + k0) = *(uint2*)outv;
}

// WK2T[512][512]: k<256: w_kc@wkC ; k>=256: w_kp@(wkC+wkS)
__global__ __launch_bounds__(256) void fold_k(const float* __restrict__ w_kc,
                                              const float* __restrict__ w_kp,
                                              const float* __restrict__ wk,
                                              u16* __restrict__ WK2T) {
    int o = blockIdx.x * 256 + threadIdx.x;
    int k0 = blockIdx.y * 4;
    bool second = k0 >= 256;
    int kb = second ? k0 - 256 : k0;
    const float* wcol = wk + o;
    float acc[4] = {0.f, 0.f, 0.f, 0.f};
    if (second) {
#pragma unroll 8
        for (int c = 0; c < 256; c++) {
            int mc = (c >> 5) * 64 + (c & 31);
            float w0 = wcol[(size_t)mc * 512] + wcol[(size_t)(mc + 32) * 512];
#pragma unroll
            for (int j = 0; j < 4; j++)
                acc[j] += w_kp[(size_t)(kb + j) * 256 + c] * w0;
        }
    } else {
#pragma unroll 8
        for (int c = 0; c < 256; c++) {
            int mc = (c >> 5) * 64 + (c & 31);
            float w0 = wcol[(size_t)mc * 512];
#pragma unroll
            for (int j = 0; j < 4; j++)
                acc[j] += w_kc[(size_t)(kb + j) * 256 + c] * w0;
        }
    }
    u16 outv[4];
#pragma unroll
    for (int j = 0; j < 4; j++) outv[j] = f2bf(acc[j]);
    *(uint2*)(WK2T + (size_t)o * 512 + k0) = *(uint2*)outv;
}

// WV2T[256][256] = (w_v @ wv)^T ; grid (1, 64), block 256
__global__ __launch_bounds__(256) void fold_v(const float* __restrict__ w_v,
                                              const float* __restrict__ wv_w,
                                              u16* __restrict__ WV2T) {
    int o = threadIdx.x;
    int k0 = blockIdx.y * 4;
    float acc[4] = {0.f, 0.f, 0.f, 0.f};
#pragma unroll 8
    for (int c = 0; c < 256; c++) {
        float w0 = wv_w[(size_t)c * 256 + o];
#pragma unroll
        for (int j = 0; j < 4; j++)
            acc[j] += w_v[(size_t)(k0 + j) * 256 + c] * w0;
    }
    u16 outv[4];
#pragma unroll
    for (int j = 0; j < 4; j++) outv[j] = f2bf(acc[j]);
    *(uint2*)(WV2T + (size_t)o * 256 + k0) = *(uint2*)outv;
}

// folded biases (f32): BQF[512], BKF[512], BVF[256]. grid 20 blocks.
__global__ __launch_bounds__(256) void fold_bias(
    const float* b_qc, const float* b_qp, const float* b_qs, const float* wq, const float* bq,
    const float* b_kc, const float* b_kp, const float* wk, const float* bk,
    const float* b_v, const float* wv_w, const float* bv,
    float* BQF, float* BKF, float* BVF) {
    __shared__ float red[4][64];
    int tid = threadIdx.x, lane = tid & 63, wave = tid >> 6;
    int blk = blockIdx.x;
    float acc = 0.f;
    if (blk < 8) {
        int o = blk * 64 + lane;
#pragma unroll 4
        for (int c = wave * 64; c < wave * 64 + 64; c++) {
            int mc = (c >> 5) * 64 + (c & 31);
            acc += (b_qc[c] + b_qp[c]) * wq[(size_t)mc * 512 + o];
            acc += b_qs[c] * wq[(size_t)(mc + 32) * 512 + o];
        }
        red[wave][lane] = acc;
        __syncthreads();
        if (wave == 0)
            BQF[o] = (bq[o] + red[0][lane] + red[1][lane] + red[2][lane] + red[3][lane]) * 0.125f;
    } else if (blk < 16) {
        int o = (blk - 8) * 64 + lane;
#pragma unroll 4
        for (int c = wave * 64; c < wave * 64 + 64; c++) {
            int mc = (c >> 5) * 64 + (c & 31);
            acc += (b_kc[c] + b_kp[c]) * wk[(size_t)mc * 512 + o];
            acc += b_kp[c] * wk[(size_t)(mc + 32) * 512 + o];
        }
        red[wave][lane] = acc;
        __syncthreads();
        if (wave == 0)
            BKF[o] = bk[o] + red[0][lane] + red[1][lane] + red[2][lane] + red[3][lane];
    } else {
        int o = (blk - 16) * 64 + lane;
#pragma unroll 4
        for (int c = wave * 64; c < wave * 64 + 64; c++)
            acc += b_v[c] * wv_w[(size_t)c * 256 + o];
        red[wave][lane] = acc;
        __syncthreads();
        if (wave == 0)
            BVF[o] = bv[o] + red[0][lane] + red[1][lane] + red[2][lane] + red[3][lane];
    }
}

// f32 -> bf16 transpose: dst[C][R] = src[R][C], 32x32 tiles
__global__ __launch_bounds__(256) void transpose_f2b(const float* __restrict__ src,
                                                     u16* __restrict__ dst, int R, int C) {
    __shared__ float tile[32][33];
    int c0 = blockIdx.x * 32, r0 = blockIdx.y * 32;
    int t = threadIdx.x;
    int j = t & 31, i0 = (t >> 5) * 4;
#pragma unroll
    for (int ii = 0; ii < 4; ii++)
        tile[i0 + ii][j] = src[(size_t)(r0 + i0 + ii) * C + c0 + j];
    __syncthreads();
    int i2 = t & 31, j0 = (t >> 5) * 4;
#pragma unroll
    for (int jj = 0; jj < 4; jj++)
        dst[(size_t)(c0 + j0 + jj) * R + r0 + i2] = f2bf(tile[i2][j0 + jj]);
}

// ---------------------------------------------------------------------------
// Main GEMM v7: BK=64 (32 MFMA between barriers, half the barrier crossings
// of BK=32), single LDS buffer, register prefetch into 8 NAMED uint4 scalars.
// C[M][N] = concat_parts(A)[M][K] @ BT[N][K]^T + bias. 128x128 tile, 4 waves.
// A: f32 (a_f32=1) or bf16. astride==256 -> part p=k0>>8 selects A0/A1/A2
// (256 % 64 == 0, so parts never straddle a K-step).
// Split-K via gridDim.z (K % (64*gridDim.z) == 0):
//   mode 0/1: gridDim.z == 1.  mode 2: f32 partial store, z=0 -> Cv, z=1 -> C2v.
// Per-thread staging: 4 A + 4 B uint4; load i covers rows i*32+(tid>>3),
// seg (tid&7)*8 — lane-consecutive threads hit consecutive 16B (coalesced).
// ---------------------------------------------------------------------------
#define APAD 72
__global__ __launch_bounds__(256) void gemm_bt(
    const void* __restrict__ A0v, const void* __restrict__ A1v, const void* __restrict__ A2v,
    int astride, int a_f32, const u16* __restrict__ BT, const float* __restrict__ bias,
    void* __restrict__ Cv, void* __restrict__ C2v, int M, int N, int K, int mode) {
    __shared__ u16 As[128 * APAD];
    __shared__ u16 Bs[128 * APAD];
    int tid = threadIdx.x;
    int wave = tid >> 6, lane = tid & 63;
    int l15 = lane & 15, quad = lane >> 4;
    int wm = (wave >> 1) * 64, wn = (wave & 1) * 64;
    int gm0 = blockIdx.x * 128, gn0 = blockIdx.y * 128;
    int kPer = K / gridDim.z;
    int kStart = blockIdx.z * kPer, kEnd = kStart + kPer;
    f32x4 acc[4][4] = {};
    int rbase = tid >> 3, seg = (tid & 7) * 8;
    uint4 tA0, tA1, tA2, tA3, tB0, tB1, tB2, tB3;

#define LD_A(I, DST)                                                                     \
    do {                                                                                 \
        int grow_ = gm0 + (I)*32 + rbase;                                                \
        if (a_f32) {                                                                     \
            const float* apf_ = (const float*)ap_;                                       \
            float4 u0_ = {0.f, 0.f, 0.f, 0.f}, u1_ = {0.f, 0.f, 0.f, 0.f};               \
            if (grow_ < M) {                                                             \
                u0_ = *(const float4*)(apf_ + (size_t)grow_ * astride + kin_ + seg);     \
                u1_ = *(const float4*)(apf_ + (size_t)grow_ * astride + kin_ + seg + 4); \
            }                                                                            \
            u16 tt_[8] = {f2bf(u0_.x), f2bf(u0_.y), f2bf(u0_.z), f2bf(u0_.w),            \
                          f2bf(u1_.x), f2bf(u1_.y), f2bf(u1_.z), f2bf(u1_.w)};           \
            DST = *(uint4*)tt_;                                                          \
        } else {                                                                         \
            uint4 v_;                                                                    \
            v_.x = v_.y = v_.z = v_.w = 0;                                               \
            if (grow_ < M)                                                               \
                v_ = *(const uint4*)((const u16*)ap_ + (size_t)grow_ * astride + kin_ + seg); \
            DST = v_;                                                                    \
        }                                                                                \
    } while (0)

#define LOADK(K0)                                                                        \
    do {                                                                                 \
        const void* ap_;                                                                 \
        int kin_;                                                                        \
        if (astride == 256) {                                                            \
            int p_ = (K0) >> 8;                                                          \
            ap_ = (p_ == 0) ? A0v : ((p_ == 1) ? A1v : A2v);                             \
            kin_ = (K0) & 255;                                                           \
        } else {                                                                         \
            ap_ = A0v;                                                                   \
            kin_ = (K0);                                                                 \
        }                                                                                \
        LD_A(0, tA0);                                                                    \
        LD_A(1, tA1);                                                                    \
        LD_A(2, tA2);                                                                    \
        LD_A(3, tA3);                                                                    \
        tB0 = *(const uint4*)(BT + (size_t)(gn0 + 0 * 32 + rbase) * K + (K0) + seg);     \
        tB1 = *(const uint4*)(BT + (size_t)(gn0 + 1 * 32 + rbase) * K + (K0) + seg);     \
        tB2 = *(const uint4*)(BT + (size_t)(gn0 + 2 * 32 + rbase) * K + (K0) + seg);     \
        tB3 = *(const uint4*)(BT + (size_t)(gn0 + 3 * 32 + rbase) * K + (K0) + seg);     \
    } while (0)

    LOADK(kStart);
    for (int k0 = kStart; k0 < kEnd; k0 += 64) {
        *(uint4*)(&As[(0 * 32 + rbase) * APAD + seg]) = tA0;
        *(uint4*)(&As[(1 * 32 + rbase) * APAD + seg]) = tA1;
        *(uint4*)(&As[(2 * 32 + rbase) * APAD + seg]) = tA2;
        *(uint4*)(&As[(3 * 32 + rbase) * APAD + seg]) = tA3;
        *(uint4*)(&Bs[(0 * 32 + rbase) * APAD + seg]) = tB0;
        *(uint4*)(&Bs[(1 * 32 + rbase) * APAD + seg]) = tB1;
        *(uint4*)(&Bs[(2 * 32 + rbase) * APAD + seg]) = tB2;
        *(uint4*)(&Bs[(3 * 32 + rbase) * APAD + seg]) = tB3;
        __syncthreads();
        if (k0 + 64 < kEnd) LOADK(k0 + 64);
#pragma unroll
        for (int ks = 0; ks < 64; ks += 32) {
            short8 afr[4], bfr[4];
#pragma unroll
            for (int i = 0; i < 4; i++)
                afr[i] = *(const short8*)(&As[(wm + i * 16 + l15) * APAD + ks + quad * 8]);
#pragma unroll
            for (int j = 0; j < 4; j++)
                bfr[j] = *(const short8*)(&Bs[(wn + j * 16 + l15) * APAD + ks + quad * 8]);
#pragma unroll
            for (int i = 0; i < 4; i++)
#pragma unroll
                for (int j = 0; j < 4; j++) acc[i][j] = MFMA16(afr[i], bfr[j], acc[i][j]);
        }
        __syncthreads();
    }
#undef LOADK
#undef LD_A
    if (mode == 2) {
        float* Cf = (float*)(blockIdx.z == 0 ? Cv : C2v);
#pragma unroll
        for (int i = 0; i < 4; i++) {
            int row = gm0 + wm + i * 16 + quad * 4;
#pragma unroll
            for (int j = 0; j < 4; j++) {
                int col = gn0 + wn + j * 16 + l15;
#pragma unroll
                for (int r = 0; r < 4; r++) {
                    int grow = row + r;
                    if (grow < M) Cf[(size_t)grow * N + col] = acc[i][j][r];
                }
            }
        }
        return;
    }
    u16* C = (u16*)Cv;
#pragma unroll
    for (int i = 0; i < 4; i++) {
        int row = gm0 + wm + i * 16 + quad * 4;
#pragma unroll
        for (int j = 0; j < 4; j++) {
            int col = gn0 + wn + j * 16 + l15;
            float bvv = bias[col];
#pragma unroll
            for (int r = 0; r < 4; r++) {
                int grow = row + r;
                if (grow < M) {
                    float v = acc[i][j][r] + bvv;
                    if (mode == 1) v = fmaxf(v, 0.f);
                    C[(size_t)grow * N + col] = f2bf(v);
                }
            }
        }
    }
}

// ---------------------------------------------------------------------------
// V transpose: VHR[(k*16+b)*256 + h*32 + d] -> VT[((b*8+h)*32+d)*2048 + k].
// ---------------------------------------------------------------------------
__global__ __launch_bounds__(256) void transpose_v(const u16* __restrict__ vhr,
                                                   u16* __restrict__ vt) {
    int k0 = blockIdx.x * 128, b = blockIdx.y, h = blockIdx.z;
    int tid = threadIdx.x;
#pragma unroll
    for (int i = 0; i < 2; i++) {
        int idx = tid * 2 + i;
        int d = idx >> 4, ks = (idx & 15) * 8;
        u16 o[8];
#pragma unroll
        for (int e = 0; e < 8; e++)
            o[e] = vhr[((size_t)(k0 + ks + e) * 16 + b) * 256 + h * 32 + d];
        *(uint4*)(vt + ((size_t)(b * 8 + h) * 32 + d) * 2048 + k0 + ks) = *(uint4*)o;
    }
}

// ---------------------------------------------------------------------------
// Attention kernel A (v2): split-K x2, swapped-operand QK, Q in regs, V from
// global VT. XCD-grouped decode. f32 partial ctx + Z.
// ---------------------------------------------------------------------------
__global__ __launch_bounds__(256, 5) void attn_a(const u16* __restrict__ qh,
                                                 const u16* __restrict__ kh,
                                                 const u16* __restrict__ vt,
                                                 float* __restrict__ ctxp,
                                                 float* __restrict__ zp) {
    int l = blockIdx.x;
    int w = (l & 7) * 160 + (l >> 3);
    int g = w / 10;
    int iw = w - g * 10;
    int kc = iw / 5;
    int qt = iw - kc * 5;
    int h = g & 7, b = g >> 3;
    __shared__ u16 Kc[64 * 72];
    __shared__ u16 Pt[64 * 72];
    int tid = threadIdx.x, wave = tid >> 6, lane = tid & 63;
    int l15 = lane & 15, quad = lane >> 4;
    int q0 = qt * 64;
    int kb0 = kc * 1024;
    short8 qf[2];
    {
        short8 qz = {};
        qf[0] = qz;
        qf[1] = qz;
        int q = q0 + wave * 16 + l15;
        if (q < 300) {
            const u16* qp = qh + ((size_t)q * 16 + b) * 512 + h * 64 + quad * 8;
            qf[0] = *(const short8*)(qp);
            qf[1] = *(const short8*)(qp + 32);
        }
    }
    const u16* kbase = kh + (size_t)kb0 * 8192 + b * 512 + h * 64;
    const u16* vbase = vt + ((size_t)(b * 8 + h) * 32) * 2048 + kb0;
    f32x4 cacc[2] = {};
    float zl = 0.f;
    for (int it = 0; it < 16; ++it) {
#pragma unroll
        for (int i2 = 0; i2 < 2; i2++) {
            int idx = tid * 2 + i2;
            int row = idx >> 3, seg = (idx & 7) * 8;
            *(uint4*)(&Kc[row * 72 + seg]) =
                *(const uint4*)(kbase + (size_t)(it * 64 + row) * 8192 + seg);
        }
        __syncthreads();
        f32x4 sacc[4] = {};
#pragma unroll
        for (int d0 = 0; d0 < 2; d0++)
#pragma unroll
            for (int t = 0; t < 4; t++) {
                short8 af = *(const short8*)(&Kc[(t * 16 + l15) * 72 + d0 * 32 + quad * 8]);
                sacc[t] = MFMA16(af, qf[d0], sacc[t]);
            }
        __syncthreads();
#pragma unroll
        for (int t = 0; t < 4; t++) {
            u16 pk[4];
#pragma unroll
            for (int r = 0; r < 4; r++) {
                float p = __expf(sacc[t][r]);
                zl += p;
                pk[r] = f2bf(p);
            }
            *(uint2*)(&Pt[(wave * 16 + l15) * 72 + t * 16 + quad * 4]) = *(uint2*)pk;
        }
#pragma unroll
        for (int kk = 0; kk < 2; kk++) {
            short8 pa = *(const short8*)(&Pt[(wave * 16 + l15) * 72 + kk * 32 + quad * 8]);
#pragma unroll
            for (int t = 0; t < 2; t++) {
                short8 bf = *(const short8*)(vbase + (size_t)(t * 16 + l15) * 2048 +
                                             it * 64 + kk * 32 + quad * 8);
                cacc[t] = MFMA16(pa, bf, cacc[t]);
            }
        }
    }
    zl += __shfl_xor(zl, 16);
    zl += __shfl_xor(zl, 32);
    if (quad == 0) {
        int q = q0 + wave * 16 + l15;
        if (q < 300) zp[((size_t)kc * 128 + b * 8 + h) * 320 + q] = zl;
    }
    float* cp = ctxp + (size_t)kc * 5120 * 256;
#pragma unroll
    for (int r = 0; r < 4; r++) {
        int q = q0 + wave * 16 + quad * 4 + r;
        if (q < 300) {
#pragma unroll
            for (int t = 0; t < 2; t++)
                cp[((size_t)q * 16 + b) * 256 + h * 32 + t * 16 + l15] = cacc[t][r];
        }
    }
}

// combine split-K partials: ctx = (c0+c1)/(z0+z1) -> bf16; z8inv = 0.125/z
__global__ __launch_bounds__(256) void attn_norm(const float* __restrict__ ctxp,
                                                 const float* __restrict__ zp,
                                                 u16* __restrict__ ctx,
                                                 float* __restrict__ z8inv) {
    int row = blockIdx.x;
    int t = threadIdx.x;
    int q = row >> 4, b = row & 15;
    int h = t >> 5;
    float c = ctxp[(size_t)row * 256 + t] + ctxp[(size_t)5120 * 256 + (size_t)row * 256 + t];
    size_t zi = ((size_t)b * 8 + h) * 320 + q;
    float z = zp[zi] + zp[(size_t)128 * 320 + zi];
    float rz = 1.0f / z;
    ctx[(size_t)row * 256 + t] = f2bf(c * rz);
    if ((t & 31) == 0) z8inv[zi] = rz * 0.125f;
}

// ---------------------------------------------------------------------------
// Attention kernel B: per (kchunk, qtile, b) — loop 8 heads, recompute logits,
// p = exp(s) * (1/(8Z)), accumulate head-average, write attn_avg (f32).
// ---------------------------------------------------------------------------
__global__ __launch_bounds__(256) void attn_b(const u16* __restrict__ qh,
                                              const u16* __restrict__ kh,
                                              const float* __restrict__ z8inv,
                                              float* __restrict__ out1) {
    int kc0 = blockIdx.x * 128, qt = blockIdx.y, b = blockIdx.z;
    __shared__ u16 Qt[64 * 72];
    __shared__ u16 Kc[128 * 72];
    int tid = threadIdx.x, wave = tid >> 6, lane = tid & 63;
    int l15 = lane & 15, quad = lane >> 4;
    int q0 = qt * 64;
    const f32x4 zf = {0.f, 0.f, 0.f, 0.f};
    float avg[8][4] = {};
    for (int h = 0; h < 8; h++) {
#pragma unroll
        for (int i = 0; i < 2; i++) {
            int idx = tid * 2 + i;
            int row = idx >> 3, seg = (idx & 7) * 8;
            uint4 v;
            v.x = v.y = v.z = v.w = 0;
            int q = q0 + row;
            if (q < 300) v = *(const uint4*)(qh + ((size_t)q * 16 + b) * 512 + h * 64 + seg);
            *(uint4*)(&Qt[row * 72 + seg]) = v;
        }
#pragma unroll
        for (int i = 0; i < 4; i++) {
            int idx = tid * 4 + i;
            int row = idx >> 3, seg = (idx & 7) * 8;
            *(uint4*)(&Kc[row * 72 + seg]) =
                *(const uint4*)(kh + ((size_t)(kc0 + row) * 16 + b) * 512 + h * 64 + seg);
        }
        __syncthreads();
        f32x4 sacc[8];
#pragma unroll
        for (int t = 0; t < 8; t++) sacc[t] = zf;
#pragma unroll
        for (int d0 = 0; d0 < 64; d0 += 32) {
            short8 af = *(const short8*)(&Qt[(wave * 16 + l15) * 72 + d0 + quad * 8]);
#pragma unroll
            for (int t = 0; t < 8; t++) {
                short8 bf = *(const short8*)(&Kc[(t * 16 + l15) * 72 + d0 + quad * 8]);
                sacc[t] = MFMA16(af, bf, sacc[t]);
            }
        }
        float zi[4];
#pragma unroll
        for (int r = 0; r < 4; r++) {
            int q = q0 + wave * 16 + quad * 4 + r;
            zi[r] = z8inv[((size_t)b * 8 + h) * 320 + (q < 319 ? q : 319)];
        }
#pragma unroll
        for (int t = 0; t < 8; t++)
#pragma unroll
            for (int r = 0; r < 4; r++) avg[t][r] += __expf(sacc[t][r]) * zi[r];
        __syncthreads();
    }
#pragma unroll
    for (int r = 0; r < 4; r++) {
        int q = q0 + wave * 16 + quad * 4 + r;
        if (q < 300) {
#pragma unroll
            for (int t = 0; t < 8; t++)
                out1[((size_t)b * 300 + q) * 2048 + kc0 + t * 16 + l15] = avg[t][r];
        }
    }
}

// residual add + LayerNorm over last dim (256). a: f32 or bf16.
// bres: if bres2 != nullptr, residual = (f32)bres + bres2 + badd[t]; else bf16 bres.
__global__ __launch_bounds__(256) void ln_kernel(const void* __restrict__ a, int a_f32,
                                                 const void* __restrict__ bres,
                                                 const float* __restrict__ bres2,
                                                 const float* __restrict__ badd,
                                                 const float* __restrict__ g,
                                                 const float* __restrict__ be,
                                                 void* __restrict__ out, int out_f32) {
    int row = blockIdx.x, t = threadIdx.x;
    float av = a_f32 ? ((const float*)a)[(size_t)row * 256 + t]
                     : bf2f(((const u16*)a)[(size_t)row * 256 + t]);
    float bv;
    if (bres2)
        bv = ((const float*)bres)[(size_t)row * 256 + t] + bres2[(size_t)row * 256 + t] + badd[t];
    else
        bv = bf2f(((const u16*)bres)[(size_t)row * 256 + t]);
    float v = av + bv;
    float s = v, sq = v * v;
#pragma unroll
    for (int o = 32; o; o >>= 1) {
        s += __shfl_xor(s, o);
        sq += __shfl_xor(sq, o);
    }
    __shared__ float red[8];
    int wave = t >> 6, lane = t & 63;
    if (lane == 0) {
        red[wave] = s;
        red[4 + wave] = sq;
    }
    __syncthreads();
    s = red[0] + red[1] + red[2] + red[3];
    sq = red[4] + red[5] + red[6] + red[7];
    float mean = s * (1.f / 256.f);
    float var = sq * (1.f / 256.f) - mean * mean;
    float rs = rsqrtf(var + 1e-5f);
    float res = (v - mean) * rs * g[t] + be[t];
    if (out_f32) ((float*)out)[(size_t)row * 256 + t] = res;
    else ((u16*)out)[(size_t)row * 256 + t] = f2bf(res);
}

// ---------------------------------------------------------------------------
extern "C" void kernel_launch(void* const* d_in, const int* in_sizes, int n_in,
                              void* d_out, int out_size, void* d_ws, size_t ws_size,
                              hipStream_t stream) {
    (void)in_sizes; (void)n_in; (void)out_size; (void)ws_size;
    const float* tgt = (const float*)d_in[0];
    const float* mem = (const float*)d_in[1];
    const float* pos = (const float*)d_in[2];
    const float* qpos = (const float*)d_in[3];
    const float* qsine = (const float*)d_in[4];
    const float* w_qc = (const float*)d_in[5];
    const float* b_qc = (const float*)d_in[6];
    const float* w_qp = (const float*)d_in[7];
    const float* b_qp = (const float*)d_in[8];
    const float* w_kc = (const float*)d_in[9];
    const float* b_kc = (const float*)d_in[10];
    const float* w_kp = (const float*)d_in[11];
    const float* b_kp = (const float*)d_in[12];
    const float* w_v = (const float*)d_in[13];
    const float* b_v = (const float*)d_in[14];
    const float* w_qs = (const float*)d_in[15];
    const float* b_qs = (const float*)d_in[16];
    const float* wq = (const float*)d_in[17];
    const float* bq = (const float*)d_in[18];
    const float* wk = (const float*)d_in[19];
    const float* bk = (const float*)d_in[20];
    const float* wv_w = (const float*)d_in[21];
    const float* bv = (const float*)d_in[22];
    const float* wo = (const float*)d_in[23];
    const float* bo = (const float*)d_in[24];
    const float* w1 = (const float*)d_in[25];
    const float* b1 = (const float*)d_in[26];
    const float* w2 = (const float*)d_in[27];
    const float* b2 = (const float*)d_in[28];
    const float* g2 = (const float*)d_in[29];
    const float* be2 = (const float*)d_in[30];
    const float* g3 = (const float*)d_in[31];
    const float* be3 = (const float*)d_in[32];

    // --- workspace layout (peak 0x2B58000 = 45.6 MB) ---
    char* ws = (char*)d_ws;
    u16* WQ3T = (u16*)(ws + 0x000000);
    u16* WK2T = (u16*)(ws + 0x0C0000);
    u16* WV2T = (u16*)(ws + 0x140000);
    u16* WOT  = (u16*)(ws + 0x160000);
    u16* W1T  = (u16*)(ws + 0x180000);
    u16* W2T  = (u16*)(ws + 0x280000);
    float* BQF = (float*)(ws + 0x380000);
    float* BKF = (float*)(ws + 0x381000);
    float* BVF = (float*)(ws + 0x382000);
    float* Z8  = (float*)(ws + 0x390000);
    u16* QH  = (u16*)(ws + 0x400000);      // [4800][512]
    u16* KH  = (u16*)(ws + 0x900000);      // [32768][512]
    u16* CTX = (u16*)(ws + 0x2900000);     // [4800][256]
    u16* TGT2 = (u16*)(ws + 0x900000);
    u16* XBUF = (u16*)(ws + 0xB60000);
    u16* HBUF = (u16*)(ws + 0x1020000);
    float* FP0 = (float*)(ws + 0x400000);
    float* FP1 = (float*)(ws + 0x22E0000);

    float* out0 = (float*)d_out;
    float* out1 = out0 + 1228800;
    u16* MB  = (u16*)out1;
    u16* PB  = MB + 8388608;
    u16* VHR = PB;
    u16* VT  = MB;
    float* CTXP = (float*)PB;
    float* ZP   = CTXP + (size_t)2 * 5120 * 256;

    cvt2<<<8192, 256, 0, stream>>>(mem, pos, MB, PB);
    fold_q<<<dim3(2, 192), 256, 0, stream>>>(w_qc, w_qp, w_qs, wq, WQ3T);
    fold_k<<<dim3(2, 128), 256, 0, stream>>>(w_kc, w_kp, wk, WK2T);
    fold_v<<<dim3(1, 64), 256, 0, stream>>>(w_v, wv_w, WV2T);
    fold_bias<<<20, 256, 0, stream>>>(b_qc, b_qp, b_qs, wq, bq, b_kc, b_kp, wk, bk,
                                      b_v, wv_w, bv, BQF, BKF, BVF);
    transpose_f2b<<<dim3(8, 8), 256, 0, stream>>>(wo, WOT, 256, 256);
    transpose_f2b<<<dim3(64, 8), 256, 0, stream>>>(w1, W1T, 256, 2048);
    transpose_f2b<<<dim3(8, 64), 256, 0, stream>>>(w2, W2T, 2048, 256);

    gemm_bt<<<dim3(38, 4), 256, 0, stream>>>(tgt, qpos, qsine, 256, 1, WQ3T, BQF, QH, nullptr, 4800, 512, 768, 0);
    gemm_bt<<<dim3(256, 4), 256, 0, stream>>>(MB, PB, nullptr, 256, 0, WK2T, BKF, KH, nullptr, 32768, 512, 512, 0);
    gemm_bt<<<dim3(256, 2), 256, 0, stream>>>(MB, nullptr, nullptr, 256, 0, WV2T, BVF, VHR, nullptr, 32768, 256, 256, 0);

    transpose_v<<<dim3(16, 16, 8), 256, 0, stream>>>(VHR, VT);
    attn_a<<<1280, 256, 0, stream>>>(QH, KH, VT, CTXP, ZP);
    attn_norm<<<4800, 256, 0, stream>>>(CTXP, ZP, CTX, Z8);
    attn_b<<<dim3(16, 5, 16), 256, 0, stream>>>(QH, KH, Z8, out1);

    gemm_bt<<<dim3(38, 2), 256, 0, stream>>>(CTX, nullptr, nullptr, 256, 0, WOT, bo, TGT2, nullptr, 4800, 256, 256, 0);
    ln_kernel<<<4800, 256, 0, stream>>>(tgt, 1, TGT2, nullptr, nullptr, g2, be2, XBUF, 0);
    gemm_bt<<<dim3(38, 16), 256, 0, stream>>>(XBUF, nullptr, nullptr, 256, 0, W1T, b1, HBUF, nullptr, 4800, 2048, 256, 1);
    gemm_bt<<<dim3(38, 2, 2), 256, 0, stream>>>(HBUF, nullptr, nullptr, 2048, 0, W2T, b2, FP0, FP1, 4800, 256, 2048, 2);
    ln_kernel<<<4800, 256, 0, stream>>>(XBUF, 0, FP0, FP1, b2, g3, be3, out0, 1);
}

// Round 9
// 521.377 us; speedup vs baseline: 1.0860x; 1.0860x over previous
//
#include <hip/hip_runtime.h>

typedef unsigned short u16;
typedef __attribute__((ext_vector_type(8))) short short8;
typedef __attribute__((ext_vector_type(4))) float f32x4;

#define MFMA16(a, b, c) __builtin_amdgcn_mfma_f32_16x16x32_bf16(a, b, c, 0, 0, 0)

__device__ __forceinline__ float bf2f(u16 u) {
    return __uint_as_float(((unsigned)u) << 16);
}
__device__ __forceinline__ u16 f2bf(float f) {
    unsigned u = __float_as_uint(f);
    u += 0x7fff + ((u >> 16) & 1);
    return (u16)(u >> 16);
}

// convert mem & pos (f32, 8388608 elems each) to bf16. grid 8192 x 256.
__global__ __launch_bounds__(256) void cvt2(const float* __restrict__ a,
                                            const float* __restrict__ b,
                                            u16* __restrict__ A, u16* __restrict__ B) {
    size_t i = ((size_t)blockIdx.x * 256 + threadIdx.x) * 4;
    float4 va = *(const float4*)(a + i);
    float4 vb = *(const float4*)(b + i);
    u16 ta[4] = {f2bf(va.x), f2bf(va.y), f2bf(va.z), f2bf(va.w)};
    u16 tb[4] = {f2bf(vb.x), f2bf(vb.y), f2bf(vb.z), f2bf(vb.w)};
    *(uint2*)(A + i) = *(uint2*)ta;
    *(uint2*)(B + i) = *(uint2*)tb;
}

// ---------------------------------------------------------------------------
// Fold kernels v3: collapse (proj -> concat -> proj) into bf16 weights stored
// TRANSPOSED ([N][K]).
// ---------------------------------------------------------------------------

// WQ3T[512][768]: k<256: w_qc@wqC ; 256..511: w_qp@wqC ; 512..767: w_qs@wqS (x 1/8)
__global__ __launch_bounds__(256) void fold_q(const float* __restrict__ w_qc,
                                              const float* __restrict__ w_qp,
                                              const float* __restrict__ w_qs,
                                              const float* __restrict__ wq,
                                              u16* __restrict__ WQ3T) {
    int o = blockIdx.x * 256 + threadIdx.x;
    int k0 = blockIdx.y * 4;
    int seg = k0 >> 8, kb = k0 & 255;
    const float* wsrc = (seg == 0) ? w_qc : ((seg == 1) ? w_qp : w_qs);
    int sOff = (seg == 2) ? 32 : 0;
    const float* wcol = wq + o;
    float acc[4] = {0.f, 0.f, 0.f, 0.f};
#pragma unroll 8
    for (int c = 0; c < 256; c++) {
        int mc = (c >> 5) * 64 + (c & 31) + sOff;
        float w0 = wcol[(size_t)mc * 512];
#pragma unroll
        for (int j = 0; j < 4; j++)
            acc[j] += wsrc[(size_t)(kb + j) * 256 + c] * w0;
    }
    u16 outv[4];
#pragma unroll
    for (int j = 0; j < 4; j++) outv[j] = f2bf(acc[j] * 0.125f);
    *(uint2*)(WQ3T + (size_t)o * 768 + k0) = *(uint2*)outv;
}

// WK2T[512][512]: k<256: w_kc@wkC ; k>=256: w_kp@(wkC+wkS)
__global__ __launch_bounds__(256) void fold_k(const float* __restrict__ w_kc,
                                              const float* __restrict__ w_kp,
                                              const float* __restrict__ wk,
                                              u16* __restrict__ WK2T) {
    int o = blockIdx.x * 256 + threadIdx.x;
    int k0 = blockIdx.y * 4;
    bool second = k0 >= 256;
    int kb = second ? k0 - 256 : k0;
    const float* wcol = wk + o;
    float acc[4] = {0.f, 0.f, 0.f, 0.f};
    if (second) {
#pragma unroll 8
        for (int c = 0; c < 256; c++) {
            int mc = (c >> 5) * 64 + (c & 31);
            float w0 = wcol[(size_t)mc * 512] + wcol[(size_t)(mc + 32) * 512];
#pragma unroll
            for (int j = 0; j < 4; j++)
                acc[j] += w_kp[(size_t)(kb + j) * 256 + c] * w0;
        }
    } else {
#pragma unroll 8
        for (int c = 0; c < 256; c++) {
            int mc = (c >> 5) * 64 + (c & 31);
            float w0 = wcol[(size_t)mc * 512];
#pragma unroll
            for (int j = 0; j < 4; j++)
                acc[j] += w_kc[(size_t)(kb + j) * 256 + c] * w0;
        }
    }
    u16 outv[4];
#pragma unroll
    for (int j = 0; j < 4; j++) outv[j] = f2bf(acc[j]);
    *(uint2*)(WK2T + (size_t)o * 512 + k0) = *(uint2*)outv;
}

// WV2T[256][256] = (w_v @ wv)^T ; grid (1, 64), block 256
__global__ __launch_bounds__(256) void fold_v(const float* __restrict__ w_v,
                                              const float* __restrict__ wv_w,
                                              u16* __restrict__ WV2T) {
    int o = threadIdx.x;
    int k0 = blockIdx.y * 4;
    float acc[4] = {0.f, 0.f, 0.f, 0.f};
#pragma unroll 8
    for (int c = 0; c < 256; c++) {
        float w0 = wv_w[(size_t)c * 256 + o];
#pragma unroll
        for (int j = 0; j < 4; j++)
            acc[j] += w_v[(size_t)(k0 + j) * 256 + c] * w0;
    }
    u16 outv[4];
#pragma unroll
    for (int j = 0; j < 4; j++) outv[j] = f2bf(acc[j]);
    *(uint2*)(WV2T + (size_t)o * 256 + k0) = *(uint2*)outv;
}

// folded biases (f32): BQF[512], BKF[512], BVF[256]. grid 20 blocks.
__global__ __launch_bounds__(256) void fold_bias(
    const float* b_qc, const float* b_qp, const float* b_qs, const float* wq, const float* bq,
    const float* b_kc, const float* b_kp, const float* wk, const float* bk,
    const float* b_v, const float* wv_w, const float* bv,
    float* BQF, float* BKF, float* BVF) {
    __shared__ float red[4][64];
    int tid = threadIdx.x, lane = tid & 63, wave = tid >> 6;
    int blk = blockIdx.x;
    float acc = 0.f;
    if (blk < 8) {
        int o = blk * 64 + lane;
#pragma unroll 4
        for (int c = wave * 64; c < wave * 64 + 64; c++) {
            int mc = (c >> 5) * 64 + (c & 31);
            acc += (b_qc[c] + b_qp[c]) * wq[(size_t)mc * 512 + o];
            acc += b_qs[c] * wq[(size_t)(mc + 32) * 512 + o];
        }
        red[wave][lane] = acc;
        __syncthreads();
        if (wave == 0)
            BQF[o] = (bq[o] + red[0][lane] + red[1][lane] + red[2][lane] + red[3][lane]) * 0.125f;
    } else if (blk < 16) {
        int o = (blk - 8) * 64 + lane;
#pragma unroll 4
        for (int c = wave * 64; c < wave * 64 + 64; c++) {
            int mc = (c >> 5) * 64 + (c & 31);
            acc += (b_kc[c] + b_kp[c]) * wk[(size_t)mc * 512 + o];
            acc += b_kp[c] * wk[(size_t)(mc + 32) * 512 + o];
        }
        red[wave][lane] = acc;
        __syncthreads();
        if (wave == 0)
            BKF[o] = bk[o] + red[0][lane] + red[1][lane] + red[2][lane] + red[3][lane];
    } else {
        int o = (blk - 16) * 64 + lane;
#pragma unroll 4
        for (int c = wave * 64; c < wave * 64 + 64; c++)
            acc += b_v[c] * wv_w[(size_t)c * 256 + o];
        red[wave][lane] = acc;
        __syncthreads();
        if (wave == 0)
            BVF[o] = bv[o] + red[0][lane] + red[1][lane] + red[2][lane] + red[3][lane];
    }
}

// f32 -> bf16 transpose: dst[C][R] = src[R][C], 32x32 tiles
__global__ __launch_bounds__(256) void transpose_f2b(const float* __restrict__ src,
                                                     u16* __restrict__ dst, int R, int C) {
    __shared__ float tile[32][33];
    int c0 = blockIdx.x * 32, r0 = blockIdx.y * 32;
    int t = threadIdx.x;
    int j = t & 31, i0 = (t >> 5) * 4;
#pragma unroll
    for (int ii = 0; ii < 4; ii++)
        tile[i0 + ii][j] = src[(size_t)(r0 + i0 + ii) * C + c0 + j];
    __syncthreads();
    int i2 = t & 31, j0 = (t >> 5) * 4;
#pragma unroll
    for (int jj = 0; jj < 4; jj++)
        dst[(size_t)(c0 + j0 + jj) * R + r0 + i2] = f2bf(tile[i2][j0 + jj]);
}

// ---------------------------------------------------------------------------
// gemm_bt (r5 version, f32-capable): single LDS buffer, register prefetch,
// BK=32, 2 barriers/step. Used ONLY for the QH GEMM (f32 A, 3 parts).
// ---------------------------------------------------------------------------
#define APAD 40
__global__ __launch_bounds__(256) void gemm_bt(
    const void* __restrict__ A0v, const void* __restrict__ A1v, const void* __restrict__ A2v,
    int astride, int a_f32, const u16* __restrict__ BT, const float* __restrict__ bias,
    void* __restrict__ Cv, void* __restrict__ C2v, int M, int N, int K, int mode) {
    __shared__ u16 As[128 * APAD];
    __shared__ u16 Bs[128 * APAD];
    int tid = threadIdx.x;
    int wave = tid >> 6, lane = tid & 63;
    int l15 = lane & 15, quad = lane >> 4;
    int wm = (wave >> 1) * 64, wn = (wave & 1) * 64;
    int gm0 = blockIdx.x * 128, gn0 = blockIdx.y * 128;
    int kPer = K / gridDim.z;
    int kStart = blockIdx.z * kPer, kEnd = kStart + kPer;
    f32x4 acc[4][4] = {};
    int row0 = (tid * 2) >> 2, seg0 = ((tid * 2) & 3) * 8;
    int row1 = (tid * 2 + 1) >> 2, seg1 = ((tid * 2 + 1) & 3) * 8;
    int growA0 = gm0 + row0, growA1 = gm0 + row1;
    uint4 tA0, tA1, tB0, tB1;

#define LOADK(K0)                                                                   \
    do {                                                                            \
        const void* ap_;                                                            \
        int kin_;                                                                   \
        if (astride == 256) {                                                       \
            int p_ = (K0) >> 8;                                                     \
            ap_ = (p_ == 0) ? A0v : ((p_ == 1) ? A1v : A2v);                        \
            kin_ = (K0) & 255;                                                      \
        } else {                                                                    \
            ap_ = A0v;                                                              \
            kin_ = (K0);                                                            \
        }                                                                           \
        if (a_f32) {                                                                \
            const float* apf_ = (const float*)ap_;                                  \
            float4 u0_ = {0.f, 0.f, 0.f, 0.f}, u1_ = {0.f, 0.f, 0.f, 0.f};          \
            if (growA0 < M) {                                                       \
                u0_ = *(const float4*)(apf_ + (size_t)growA0 * astride + kin_ + seg0);     \
                u1_ = *(const float4*)(apf_ + (size_t)growA0 * astride + kin_ + seg0 + 4); \
            }                                                                       \
            u16 t0_[8] = {f2bf(u0_.x), f2bf(u0_.y), f2bf(u0_.z), f2bf(u0_.w),       \
                          f2bf(u1_.x), f2bf(u1_.y), f2bf(u1_.z), f2bf(u1_.w)};      \
            tA0 = *(uint4*)t0_;                                                     \
            float4 u2_ = {0.f, 0.f, 0.f, 0.f}, u3_ = {0.f, 0.f, 0.f, 0.f};          \
            if (growA1 < M) {                                                       \
                u2_ = *(const float4*)(apf_ + (size_t)growA1 * astride + kin_ + seg1);     \
                u3_ = *(const float4*)(apf_ + (size_t)growA1 * astride + kin_ + seg1 + 4); \
            }                                                                       \
            u16 t1_[8] = {f2bf(u2_.x), f2bf(u2_.y), f2bf(u2_.z), f2bf(u2_.w),       \
                          f2bf(u3_.x), f2bf(u3_.y), f2bf(u3_.z), f2bf(u3_.w)};      \
            tA1 = *(uint4*)t1_;                                                     \
        } else {                                                                    \
            uint4 v_;                                                               \
            v_.x = v_.y = v_.z = v_.w = 0;                                          \
            if (growA0 < M)                                                         \
                v_ = *(const uint4*)((const u16*)ap_ + (size_t)growA0 * astride + kin_ + seg0); \
            tA0 = v_;                                                               \
            v_.x = v_.y = v_.z = v_.w = 0;                                          \
            if (growA1 < M)                                                         \
                v_ = *(const uint4*)((const u16*)ap_ + (size_t)growA1 * astride + kin_ + seg1); \
            tA1 = v_;                                                               \
        }                                                                           \
        tB0 = *(const uint4*)(BT + (size_t)(gn0 + row0) * K + (K0) + seg0);         \
        tB1 = *(const uint4*)(BT + (size_t)(gn0 + row1) * K + (K0) + seg1);         \
    } while (0)

    LOADK(kStart);
    for (int k0 = kStart; k0 < kEnd; k0 += 32) {
        *(uint4*)(&As[row0 * APAD + seg0]) = tA0;
        *(uint4*)(&Bs[row0 * APAD + seg0]) = tB0;
        *(uint4*)(&As[row1 * APAD + seg1]) = tA1;
        *(uint4*)(&Bs[row1 * APAD + seg1]) = tB1;
        __syncthreads();
        if (k0 + 32 < kEnd) LOADK(k0 + 32);
        short8 afr[4], bfr[4];
#pragma unroll
        for (int i = 0; i < 4; i++)
            afr[i] = *(const short8*)(&As[(wm + i * 16 + l15) * APAD + quad * 8]);
#pragma unroll
        for (int j = 0; j < 4; j++)
            bfr[j] = *(const short8*)(&Bs[(wn + j * 16 + l15) * APAD + quad * 8]);
#pragma unroll
        for (int i = 0; i < 4; i++)
#pragma unroll
            for (int j = 0; j < 4; j++) acc[i][j] = MFMA16(afr[i], bfr[j], acc[i][j]);
        __syncthreads();
    }
#undef LOADK
    if (mode == 2) {
        float* Cf = (float*)(blockIdx.z == 0 ? Cv : C2v);
#pragma unroll
        for (int i = 0; i < 4; i++) {
            int row = gm0 + wm + i * 16 + quad * 4;
#pragma unroll
            for (int j = 0; j < 4; j++) {
                int col = gn0 + wn + j * 16 + l15;
#pragma unroll
                for (int r = 0; r < 4; r++) {
                    int grow = row + r;
                    if (grow < M) Cf[(size_t)grow * N + col] = acc[i][j][r];
                }
            }
        }
        return;
    }
    u16* C = (u16*)Cv;
#pragma unroll
    for (int i = 0; i < 4; i++) {
        int row = gm0 + wm + i * 16 + quad * 4;
#pragma unroll
        for (int j = 0; j < 4; j++) {
            int col = gn0 + wn + j * 16 + l15;
            float bvv = bias[col];
#pragma unroll
            for (int r = 0; r < 4; r++) {
                int grow = row + r;
                if (grow < M) {
                    float v = acc[i][j][r] + bvv;
                    if (mode == 1) v = fmaxf(v, 0.f);
                    C[(size_t)grow * N + col] = f2bf(v);
                }
            }
        }
    }
}

// ---------------------------------------------------------------------------
// gemm_ld: bf16-A GEMM with __builtin_amdgcn_global_load_lds width=16 staging
// (m97 structure: direct global->LDS, loads drain once at barrier — no VGPR
// round-trip, no per-iter vmcnt stalls). 128x128 tile, BK=32, 4 waves.
// LDS tiles UNPADDED [128][32]; dest is linear (wave-uniform base + lane*16);
// bank spread via XOR pre-swizzle of the GLOBAL source chunk (rule #21:
// linear dest + inverse-swz source + same swz on read).
// A parts: astride==256 && K==512 -> k0&256 selects A1 (KH concat); else A0.
// M edge: source row clamped to M-1 (garbage rows never stored).
// mode 0/1/2 as gemm_bt. Split-K via gridDim.z.
// ---------------------------------------------------------------------------
__global__ __launch_bounds__(256) void gemm_ld(
    const u16* __restrict__ A0, const u16* __restrict__ A1,
    int astride, const u16* __restrict__ BT, const float* __restrict__ bias,
    void* __restrict__ Cv, void* __restrict__ C2v, int M, int N, int K, int mode) {
    __shared__ u16 As[128 * 32];
    __shared__ u16 Bs[128 * 32];
    int tid = threadIdx.x;
    int wave = tid >> 6, lane = tid & 63;
    int l15 = lane & 15, quad = lane >> 4;
    int wm = (wave >> 1) * 64, wn = (wave & 1) * 64;
    int gm0 = blockIdx.x * 128, gn0 = blockIdx.y * 128;
    int kPer = K / gridDim.z;
    int kStart = blockIdx.z * kPer, kEnd = kStart + kPer;
    f32x4 acc[4][4] = {};
    int rl = lane >> 2, slot = lane & 3;   // lane's LDS landing: row rl, 16B slot
    for (int k0 = kStart; k0 < kEnd; k0 += 32) {
        const u16* ap;
        int kin;
        if (astride == 256) {
            ap = (k0 & 256) ? A1 : A0;
            kin = k0 & 255;
        } else {
            ap = A0;
            kin = k0;
        }
#pragma unroll
        for (int is = 0; is < 2; is++) {
            int r = is * 64 + wave * 16 + rl;                 // tile row this lane fills
            int sw = (slot ^ ((r >> 1) & 3)) * 8;             // pre-swizzled source chunk
            int ga = gm0 + r;
            ga = ga < M ? ga : M - 1;
            __builtin_amdgcn_global_load_lds(
                (const __attribute__((address_space(1))) void*)(ap + (size_t)ga * astride + kin + sw),
                (__attribute__((address_space(3))) void*)&As[(is * 64 + wave * 16) * 32],
                16, 0, 0);
            __builtin_amdgcn_global_load_lds(
                (const __attribute__((address_space(1))) void*)(BT + (size_t)(gn0 + r) * K + k0 + sw),
                (__attribute__((address_space(3))) void*)&Bs[(is * 64 + wave * 16) * 32],
                16, 0, 0);
        }
        __syncthreads();   // drains vmcnt -> tiles ready
        short8 afr[4], bfr[4];
#pragma unroll
        for (int i = 0; i < 4; i++) {
            int rr = wm + i * 16 + l15;
            afr[i] = *(const short8*)(&As[rr * 32 + (quad ^ ((rr >> 1) & 3)) * 8]);
        }
#pragma unroll
        for (int j = 0; j < 4; j++) {
            int rr = wn + j * 16 + l15;
            bfr[j] = *(const short8*)(&Bs[rr * 32 + (quad ^ ((rr >> 1) & 3)) * 8]);
        }
#pragma unroll
        for (int i = 0; i < 4; i++)
#pragma unroll
            for (int j = 0; j < 4; j++) acc[i][j] = MFMA16(afr[i], bfr[j], acc[i][j]);
        __syncthreads();   // safe to overwrite tiles
    }
    if (mode == 2) {
        float* Cf = (float*)(blockIdx.z == 0 ? Cv : C2v);
#pragma unroll
        for (int i = 0; i < 4; i++) {
            int row = gm0 + wm + i * 16 + quad * 4;
#pragma unroll
            for (int j = 0; j < 4; j++) {
                int col = gn0 + wn + j * 16 + l15;
#pragma unroll
                for (int r = 0; r < 4; r++) {
                    int grow = row + r;
                    if (grow < M) Cf[(size_t)grow * N + col] = acc[i][j][r];
                }
            }
        }
        return;
    }
    u16* C = (u16*)Cv;
#pragma unroll
    for (int i = 0; i < 4; i++) {
        int row = gm0 + wm + i * 16 + quad * 4;
#pragma unroll
        for (int j = 0; j < 4; j++) {
            int col = gn0 + wn + j * 16 + l15;
            float bvv = bias[col];
#pragma unroll
            for (int r = 0; r < 4; r++) {
                int grow = row + r;
                if (grow < M) {
                    float v = acc[i][j][r] + bvv;
                    if (mode == 1) v = fmaxf(v, 0.f);
                    C[(size_t)grow * N + col] = f2bf(v);
                }
            }
        }
    }
}

// ---------------------------------------------------------------------------
// V transpose: VHR[(k*16+b)*256 + h*32 + d] -> VT[((b*8+h)*32+d)*2048 + k].
// ---------------------------------------------------------------------------
__global__ __launch_bounds__(256) void transpose_v(const u16* __restrict__ vhr,
                                                   u16* __restrict__ vt) {
    int k0 = blockIdx.x * 128, b = blockIdx.y, h = blockIdx.z;
    int tid = threadIdx.x;
#pragma unroll
    for (int i = 0; i < 2; i++) {
        int idx = tid * 2 + i;
        int d = idx >> 4, ks = (idx & 15) * 8;
        u16 o[8];
#pragma unroll
        for (int e = 0; e < 8; e++)
            o[e] = vhr[((size_t)(k0 + ks + e) * 16 + b) * 256 + h * 32 + d];
        *(uint4*)(vt + ((size_t)(b * 8 + h) * 32 + d) * 2048 + k0 + ks) = *(uint4*)o;
    }
}

// ---------------------------------------------------------------------------
// Attention kernel A (v2): split-K x2, swapped-operand QK, Q in regs, V from
// global VT. XCD-grouped decode. f32 partial ctx + Z.
// ---------------------------------------------------------------------------
__global__ __launch_bounds__(256, 5) void attn_a(const u16* __restrict__ qh,
                                                 const u16* __restrict__ kh,
                                                 const u16* __restrict__ vt,
                                                 float* __restrict__ ctxp,
                                                 float* __restrict__ zp) {
    int l = blockIdx.x;
    int w = (l & 7) * 160 + (l >> 3);
    int g = w / 10;
    int iw = w - g * 10;
    int kc = iw / 5;
    int qt = iw - kc * 5;
    int h = g & 7, b = g >> 3;
    __shared__ u16 Kc[64 * 72];
    __shared__ u16 Pt[64 * 72];
    int tid = threadIdx.x, wave = tid >> 6, lane = tid & 63;
    int l15 = lane & 15, quad = lane >> 4;
    int q0 = qt * 64;
    int kb0 = kc * 1024;
    short8 qf[2];
    {
        short8 qz = {};
        qf[0] = qz;
        qf[1] = qz;
        int q = q0 + wave * 16 + l15;
        if (q < 300) {
            const u16* qp = qh + ((size_t)q * 16 + b) * 512 + h * 64 + quad * 8;
            qf[0] = *(const short8*)(qp);
            qf[1] = *(const short8*)(qp + 32);
        }
    }
    const u16* kbase = kh + (size_t)kb0 * 8192 + b * 512 + h * 64;
    const u16* vbase = vt + ((size_t)(b * 8 + h) * 32) * 2048 + kb0;
    f32x4 cacc[2] = {};
    float zl = 0.f;
    for (int it = 0; it < 16; ++it) {
#pragma unroll
        for (int i2 = 0; i2 < 2; i2++) {
            int idx = tid * 2 + i2;
            int row = idx >> 3, seg = (idx & 7) * 8;
            *(uint4*)(&Kc[row * 72 + seg]) =
                *(const uint4*)(kbase + (size_t)(it * 64 + row) * 8192 + seg);
        }
        __syncthreads();
        f32x4 sacc[4] = {};
#pragma unroll
        for (int d0 = 0; d0 < 2; d0++)
#pragma unroll
            for (int t = 0; t < 4; t++) {
                short8 af = *(const short8*)(&Kc[(t * 16 + l15) * 72 + d0 * 32 + quad * 8]);
                sacc[t] = MFMA16(af, qf[d0], sacc[t]);
            }
        __syncthreads();
#pragma unroll
        for (int t = 0; t < 4; t++) {
            u16 pk[4];
#pragma unroll
            for (int r = 0; r < 4; r++) {
                float p = __expf(sacc[t][r]);
                zl += p;
                pk[r] = f2bf(p);
            }
            *(uint2*)(&Pt[(wave * 16 + l15) * 72 + t * 16 + quad * 4]) = *(uint2*)pk;
        }
#pragma unroll
        for (int kk = 0; kk < 2; kk++) {
            short8 pa = *(const short8*)(&Pt[(wave * 16 + l15) * 72 + kk * 32 + quad * 8]);
#pragma unroll
            for (int t = 0; t < 2; t++) {
                short8 bf = *(const short8*)(vbase + (size_t)(t * 16 + l15) * 2048 +
                                             it * 64 + kk * 32 + quad * 8);
                cacc[t] = MFMA16(pa, bf, cacc[t]);
            }
        }
    }
    zl += __shfl_xor(zl, 16);
    zl += __shfl_xor(zl, 32);
    if (quad == 0) {
        int q = q0 + wave * 16 + l15;
        if (q < 300) zp[((size_t)kc * 128 + b * 8 + h) * 320 + q] = zl;
    }
    float* cp = ctxp + (size_t)kc * 5120 * 256;
#pragma unroll
    for (int r = 0; r < 4; r++) {
        int q = q0 + wave * 16 + quad * 4 + r;
        if (q < 300) {
#pragma unroll
            for (int t = 0; t < 2; t++)
                cp[((size_t)q * 16 + b) * 256 + h * 32 + t * 16 + l15] = cacc[t][r];
        }
    }
}

// combine split-K partials: ctx = (c0+c1)/(z0+z1) -> bf16; z8inv = 0.125/z
__global__ __launch_bounds__(256) void attn_norm(const float* __restrict__ ctxp,
                                                 const float* __restrict__ zp,
                                                 u16* __restrict__ ctx,
                                                 float* __restrict__ z8inv) {
    int row = blockIdx.x;
    int t = threadIdx.x;
    int q = row >> 4, b = row & 15;
    int h = t >> 5;
    float c = ctxp[(size_t)row * 256 + t] + ctxp[(size_t)5120 * 256 + (size_t)row * 256 + t];
    size_t zi = ((size_t)b * 8 + h) * 320 + q;
    float z = zp[zi] + zp[(size_t)128 * 320 + zi];
    float rz = 1.0f / z;
    ctx[(size_t)row * 256 + t] = f2bf(c * rz);
    if ((t & 31) == 0) z8inv[zi] = rz * 0.125f;
}

// ---------------------------------------------------------------------------
// Attention kernel B: per (kchunk, qtile, b) — loop 8 heads, recompute logits,
// p = exp(s) * (1/(8Z)), accumulate head-average, write attn_avg (f32).
// ---------------------------------------------------------------------------
__global__ __launch_bounds__(256) void attn_b(const u16* __restrict__ qh,
                                              const u16* __restrict__ kh,
                                              const float* __restrict__ z8inv,
                                              float* __restrict__ out1) {
    int kc0 = blockIdx.x * 128, qt = blockIdx.y, b = blockIdx.z;
    __shared__ u16 Qt[64 * 72];
    __shared__ u16 Kc[128 * 72];
    int tid = threadIdx.x, wave = tid >> 6, lane = tid & 63;
    int l15 = lane & 15, quad = lane >> 4;
    int q0 = qt * 64;
    const f32x4 zf = {0.f, 0.f, 0.f, 0.f};
    float avg[8][4] = {};
    for (int h = 0; h < 8; h++) {
#pragma unroll
        for (int i = 0; i < 2; i++) {
            int idx = tid * 2 + i;
            int row = idx >> 3, seg = (idx & 7) * 8;
            uint4 v;
            v.x = v.y = v.z = v.w = 0;
            int q = q0 + row;
            if (q < 300) v = *(const uint4*)(qh + ((size_t)q * 16 + b) * 512 + h * 64 + seg);
            *(uint4*)(&Qt[row * 72 + seg]) = v;
        }
#pragma unroll
        for (int i = 0; i < 4; i++) {
            int idx = tid * 4 + i;
            int row = idx >> 3, seg = (idx & 7) * 8;
            *(uint4*)(&Kc[row * 72 + seg]) =
                *(const uint4*)(kh + ((size_t)(kc0 + row) * 16 + b) * 512 + h * 64 + seg);
        }
        __syncthreads();
        f32x4 sacc[8];
#pragma unroll
        for (int t = 0; t < 8; t++) sacc[t] = zf;
#pragma unroll
        for (int d0 = 0; d0 < 64; d0 += 32) {
            short8 af = *(const short8*)(&Qt[(wave * 16 + l15) * 72 + d0 + quad * 8]);
#pragma unroll
            for (int t = 0; t < 8; t++) {
                short8 bf = *(const short8*)(&Kc[(t * 16 + l15) * 72 + d0 + quad * 8]);
                sacc[t] = MFMA16(af, bf, sacc[t]);
            }
        }
        float zi[4];
#pragma unroll
        for (int r = 0; r < 4; r++) {
            int q = q0 + wave * 16 + quad * 4 + r;
            zi[r] = z8inv[((size_t)b * 8 + h) * 320 + (q < 319 ? q : 319)];
        }
#pragma unroll
        for (int t = 0; t < 8; t++)
#pragma unroll
            for (int r = 0; r < 4; r++) avg[t][r] += __expf(sacc[t][r]) * zi[r];
        __syncthreads();
    }
#pragma unroll
    for (int r = 0; r < 4; r++) {
        int q = q0 + wave * 16 + quad * 4 + r;
        if (q < 300) {
#pragma unroll
            for (int t = 0; t < 8; t++)
                out1[((size_t)b * 300 + q) * 2048 + kc0 + t * 16 + l15] = avg[t][r];
        }
    }
}

// residual add + LayerNorm over last dim (256). a: f32 or bf16.
// bres: if bres2 != nullptr, residual = (f32)bres + bres2 + badd[t]; else bf16 bres.
__global__ __launch_bounds__(256) void ln_kernel(const void* __restrict__ a, int a_f32,
                                                 const void* __restrict__ bres,
                                                 const float* __restrict__ bres2,
                                                 const float* __restrict__ badd,
                                                 const float* __restrict__ g,
                                                 const float* __restrict__ be,
                                                 void* __restrict__ out, int out_f32) {
    int row = blockIdx.x, t = threadIdx.x;
    float av = a_f32 ? ((const float*)a)[(size_t)row * 256 + t]
                     : bf2f(((const u16*)a)[(size_t)row * 256 + t]);
    float bv;
    if (bres2)
        bv = ((const float*)bres)[(size_t)row * 256 + t] + bres2[(size_t)row * 256 + t] + badd[t];
    else
        bv = bf2f(((const u16*)bres)[(size_t)row * 256 + t]);
    float v = av + bv;
    float s = v, sq = v * v;
#pragma unroll
    for (int o = 32; o; o >>= 1) {
        s += __shfl_xor(s, o);
        sq += __shfl_xor(sq, o);
    }
    __shared__ float red[8];
    int wave = t >> 6, lane = t & 63;
    if (lane == 0) {
        red[wave] = s;
        red[4 + wave] = sq;
    }
    __syncthreads();
    s = red[0] + red[1] + red[2] + red[3];
    sq = red[4] + red[5] + red[6] + red[7];
    float mean = s * (1.f / 256.f);
    float var = sq * (1.f / 256.f) - mean * mean;
    float rs = rsqrtf(var + 1e-5f);
    float res = (v - mean) * rs * g[t] + be[t];
    if (out_f32) ((float*)out)[(size_t)row * 256 + t] = res;
    else ((u16*)out)[(size_t)row * 256 + t] = f2bf(res);
}

// ---------------------------------------------------------------------------
extern "C" void kernel_launch(void* const* d_in, const int* in_sizes, int n_in,
                              void* d_out, int out_size, void* d_ws, size_t ws_size,
                              hipStream_t stream) {
    (void)in_sizes; (void)n_in; (void)out_size; (void)ws_size;
    const float* tgt = (const float*)d_in[0];
    const float* mem = (const float*)d_in[1];
    const float* pos = (const float*)d_in[2];
    const float* qpos = (const float*)d_in[3];
    const float* qsine = (const float*)d_in[4];
    const float* w_qc = (const float*)d_in[5];
    const float* b_qc = (const float*)d_in[6];
    const float* w_qp = (const float*)d_in[7];
    const float* b_qp = (const float*)d_in[8];
    const float* w_kc = (const float*)d_in[9];
    const float* b_kc = (const float*)d_in[10];
    const float* w_kp = (const float*)d_in[11];
    const float* b_kp = (const float*)d_in[12];
    const float* w_v = (const float*)d_in[13];
    const float* b_v = (const float*)d_in[14];
    const float* w_qs = (const float*)d_in[15];
    const float* b_qs = (const float*)d_in[16];
    const float* wq = (const float*)d_in[17];
    const float* bq = (const float*)d_in[18];
    const float* wk = (const float*)d_in[19];
    const float* bk = (const float*)d_in[20];
    const float* wv_w = (const float*)d_in[21];
    const float* bv = (const float*)d_in[22];
    const float* wo = (const float*)d_in[23];
    const float* bo = (const float*)d_in[24];
    const float* w1 = (const float*)d_in[25];
    const float* b1 = (const float*)d_in[26];
    const float* w2 = (const float*)d_in[27];
    const float* b2 = (const float*)d_in[28];
    const float* g2 = (const float*)d_in[29];
    const float* be2 = (const float*)d_in[30];
    const float* g3 = (const float*)d_in[31];
    const float* be3 = (const float*)d_in[32];

    // --- workspace layout (peak 0x2B58000 = 45.6 MB) ---
    char* ws = (char*)d_ws;
    u16* WQ3T = (u16*)(ws + 0x000000);
    u16* WK2T = (u16*)(ws + 0x0C0000);
    u16* WV2T = (u16*)(ws + 0x140000);
    u16* WOT  = (u16*)(ws + 0x160000);
    u16* W1T  = (u16*)(ws + 0x180000);
    u16* W2T  = (u16*)(ws + 0x280000);
    float* BQF = (float*)(ws + 0x380000);
    float* BKF = (float*)(ws + 0x381000);
    float* BVF = (float*)(ws + 0x382000);
    float* Z8  = (float*)(ws + 0x390000);
    u16* QH  = (u16*)(ws + 0x400000);      // [4800][512]
    u16* KH  = (u16*)(ws + 0x900000);      // [32768][512]
    u16* CTX = (u16*)(ws + 0x2900000);     // [4800][256]
    u16* TGT2 = (u16*)(ws + 0x900000);
    u16* XBUF = (u16*)(ws + 0xB60000);
    u16* HBUF = (u16*)(ws + 0x1020000);
    float* FP0 = (float*)(ws + 0x400000);
    float* FP1 = (float*)(ws + 0x22E0000);

    float* out0 = (float*)d_out;
    float* out1 = out0 + 1228800;
    u16* MB  = (u16*)out1;
    u16* PB  = MB + 8388608;
    u16* VHR = PB;
    u16* VT  = MB;
    float* CTXP = (float*)PB;
    float* ZP   = CTXP + (size_t)2 * 5120 * 256;

    cvt2<<<8192, 256, 0, stream>>>(mem, pos, MB, PB);
    fold_q<<<dim3(2, 192), 256, 0, stream>>>(w_qc, w_qp, w_qs, wq, WQ3T);
    fold_k<<<dim3(2, 128), 256, 0, stream>>>(w_kc, w_kp, wk, WK2T);
    fold_v<<<dim3(1, 64), 256, 0, stream>>>(w_v, wv_w, WV2T);
    fold_bias<<<20, 256, 0, stream>>>(b_qc, b_qp, b_qs, wq, bq, b_kc, b_kp, wk, bk,
                                      b_v, wv_w, bv, BQF, BKF, BVF);
    transpose_f2b<<<dim3(8, 8), 256, 0, stream>>>(wo, WOT, 256, 256);
    transpose_f2b<<<dim3(64, 8), 256, 0, stream>>>(w1, W1T, 256, 2048);
    transpose_f2b<<<dim3(8, 64), 256, 0, stream>>>(w2, W2T, 2048, 256);

    gemm_bt<<<dim3(38, 4), 256, 0, stream>>>(tgt, qpos, qsine, 256, 1, WQ3T, BQF, QH, nullptr, 4800, 512, 768, 0);
    gemm_ld<<<dim3(256, 4), 256, 0, stream>>>(MB, PB, 256, WK2T, BKF, KH, nullptr, 32768, 512, 512, 0);
    gemm_ld<<<dim3(256, 2), 256, 0, stream>>>(MB, MB, 256, WV2T, BVF, VHR, nullptr, 32768, 256, 256, 0);

    transpose_v<<<dim3(16, 16, 8), 256, 0, stream>>>(VHR, VT);
    attn_a<<<1280, 256, 0, stream>>>(QH, KH, VT, CTXP, ZP);
    attn_norm<<<4800, 256, 0, stream>>>(CTXP, ZP, CTX, Z8);
    attn_b<<<dim3(16, 5, 16), 256, 0, stream>>>(QH, KH, Z8, out1);

    gemm_ld<<<dim3(38, 2), 256, 0, stream>>>(CTX, CTX, 256, WOT, bo, TGT2, nullptr, 4800, 256, 256, 0);
    ln_kernel<<<4800, 256, 0, stream>>>(tgt, 1, TGT2, nullptr, nullptr, g2, be2, XBUF, 0);
    gemm_ld<<<dim3(38, 16), 256, 0, stream>>>(XBUF, XBUF, 256, W1T, b1, HBUF, nullptr, 4800, 2048, 256, 1);
    gemm_ld<<<dim3(38, 2, 2), 256, 0, stream>>>(HBUF, HBUF, 2048, W2T, b2, FP0, FP1, 4800, 256, 2048, 2);
    ln_kernel<<<4800, 256, 0, stream>>>(XBUF, 0, FP0, FP1, b2, g3, be3, out0, 1);
}